// Round 1
// baseline (490.690 us; speedup 1.0000x reference)
//
#include <hip/hip_runtime.h>
#include <cstdint>
#include <cstddef>

// TransformerBlock on MI355X (gfx950).
// x:[2,2048,1024] fp32. bf16 MFMA (16x16x32) for all GEMMs + flash attention,
// fp32 accumulation, fp32 residual spine.
//
// Stage layout decisions:
//  - Weights converted+transposed once per call to bf16 [N][K] so both A and B
//    MFMA fragments are K-contiguous 16B reads.
//  - GEMM: 128x128 tile, BK=64, 4 waves (2x2 of 64x64), LDS stride 72 bf16
//    (144B = 16B-aligned rows, bank rotation 4/row -> 2-way conflict = free).
//  - Attention: per block one (b,h) + 64 Q rows; each wave owns 16 Q rows so
//    online-softmax state is wave-private (no cross-wave sync; waves have
//    different causal trip counts so __syncthreads is illegal here).
//    Q/K fragments read directly from qkv, V^T fragments from vt buffer.
//    P goes C-layout -> LDS -> A-layout (m120-verified transform).

#define D_MODEL 1024
#define TSEQ    2048
#define BATCH   2
#define NHEADS  16
#define NTOK    (BATCH*TSEQ)   // 4096

typedef __attribute__((ext_vector_type(8))) short bf16x8;
typedef __attribute__((ext_vector_type(4))) float f32x4;
typedef unsigned short ushort_t;

__device__ __forceinline__ unsigned short f2bf(float f){
  union { float f; unsigned u; } v; v.f = f;
  unsigned r = v.u + 0x7fffu + ((v.u >> 16) & 1u);
  return (unsigned short)(r >> 16);
}

// ---------------- weight convert + transpose: fp32 [K][N] -> bf16 [N][K] ----
__global__ __launch_bounds__(256) void wtrans(const float* __restrict__ in,
                                              ushort_t* __restrict__ out,
                                              int K, int N){
  __shared__ float tile[32][33];
  int n0 = blockIdx.x*32, k0 = blockIdx.y*32;
  int tx = threadIdx.x, ty = threadIdx.y;   // 32 x 8
  #pragma unroll
  for (int i=0;i<32;i+=8)
    tile[ty+i][tx] = in[(size_t)(k0+ty+i)*N + n0+tx];
  __syncthreads();
  #pragma unroll
  for (int i=0;i<32;i+=8)
    out[(size_t)(n0+ty+i)*K + k0+tx] = f2bf(tile[tx][ty+i]);
}

// ---------------- layernorm: fp32 row[1024] -> bf16 ------------------------
__global__ __launch_bounds__(256) void ln_kernel(const float* __restrict__ x,
                                                 const float* __restrict__ w,
                                                 const float* __restrict__ b,
                                                 ushort_t* __restrict__ out){
  int row = blockIdx.x;
  int tid = threadIdx.x;
  const float* xr = x + (size_t)row*D_MODEL;
  float4 v = ((const float4*)xr)[tid];
  float s  = v.x+v.y+v.z+v.w;
  float s2 = v.x*v.x+v.y*v.y+v.z*v.z+v.w*v.w;
  #pragma unroll
  for (int off=1; off<64; off<<=1){ s += __shfl_xor(s,off); s2 += __shfl_xor(s2,off); }
  __shared__ float ss[4], ss2[4];
  int wave = tid>>6, lane = tid&63;
  if (lane==0){ ss[wave]=s; ss2[wave]=s2; }
  __syncthreads();
  s  = ss[0]+ss[1]+ss[2]+ss[3];
  s2 = ss2[0]+ss2[1]+ss2[2]+ss2[3];
  float mu  = s * (1.0f/D_MODEL);
  float var = s2 * (1.0f/D_MODEL) - mu*mu;
  float rstd = rsqrtf(var + 1e-5f);
  float4 wv = ((const float4*)w)[tid];
  float4 bv = ((const float4*)b)[tid];
  union { unsigned short us[4]; uint2 u2; } pk;
  pk.us[0] = f2bf((v.x-mu)*rstd*wv.x + bv.x);
  pk.us[1] = f2bf((v.y-mu)*rstd*wv.y + bv.y);
  pk.us[2] = f2bf((v.z-mu)*rstd*wv.z + bv.z);
  pk.us[3] = f2bf((v.w-mu)*rstd*wv.w + bv.w);
  *(uint2*)(out + (size_t)row*D_MODEL + tid*4) = pk.u2;
}

// ---------------- GEMM: C[M,N] = A[M,K]bf16 * BT[N,K]bf16^T + epilogue -----
// MODE 0: out bf16 = acc + bias
// MODE 1: out f32  = acc + bias + res
// MODE 2: out bf16 = gelu(acc + bias)        (exact erf gelu)
#define LDSS 72
template<int MODE>
__global__ __launch_bounds__(256) void gemm_bt(const ushort_t* __restrict__ A,
                                               const ushort_t* __restrict__ BT,
                                               const float* __restrict__ bias,
                                               const float* __restrict__ res,
                                               void* __restrict__ out,
                                               int M, int N, int K){
  __shared__ __align__(16) ushort_t As[128*LDSS];
  __shared__ __align__(16) ushort_t Bs[128*LDSS];
  const int m0 = blockIdx.x*128, n0 = blockIdx.y*128;
  const int tid = threadIdx.x;
  const int wave = tid >> 6, lane = tid & 63;
  const int wm = (wave >> 1)*64, wn = (wave & 1)*64;
  const int quad = lane >> 4, l16 = lane & 15;

  f32x4 acc[4][4] = {};

  for (int k0 = 0; k0 < K; k0 += 64) {
    #pragma unroll
    for (int c = 0; c < 4; ++c) {
      int lin = c*256 + tid;
      int row = lin >> 3, col = (lin & 7) << 3;
      uint4 va = *(const uint4*)(A  + (size_t)(m0 + row)*K + k0 + col);
      uint4 vb = *(const uint4*)(BT + (size_t)(n0 + row)*K + k0 + col);
      *(uint4*)(&As[row*LDSS + col]) = va;
      *(uint4*)(&Bs[row*LDSS + col]) = vb;
    }
    __syncthreads();
    #pragma unroll
    for (int kk = 0; kk < 64; kk += 32) {
      bf16x8 af[4], bfr[4];
      #pragma unroll
      for (int i = 0; i < 4; ++i)
        af[i]  = *(const bf16x8*)(&As[(wm + i*16 + l16)*LDSS + kk + quad*8]);
      #pragma unroll
      for (int i = 0; i < 4; ++i)
        bfr[i] = *(const bf16x8*)(&Bs[(wn + i*16 + l16)*LDSS + kk + quad*8]);
      #pragma unroll
      for (int mi = 0; mi < 4; ++mi)
        #pragma unroll
        for (int ni = 0; ni < 4; ++ni)
          acc[mi][ni] = __builtin_amdgcn_mfma_f32_16x16x32_bf16(af[mi], bfr[ni], acc[mi][ni], 0,0,0);
    }
    __syncthreads();
  }

  #pragma unroll
  for (int ni = 0; ni < 4; ++ni){
    int col = n0 + wn + ni*16 + l16;
    float bv = bias[col];
    #pragma unroll
    for (int mi = 0; mi < 4; ++mi){
      #pragma unroll
      for (int r = 0; r < 4; ++r){
        int row = m0 + wm + mi*16 + quad*4 + r;
        float v = acc[mi][ni][r] + bv;
        if constexpr (MODE == 1){
          ((float*)out)[(size_t)row*N + col] = v + res[(size_t)row*N + col];
        } else if constexpr (MODE == 2){
          float g = 0.5f*v*(1.0f + erff(v*0.70710678118654752f));
          ((ushort_t*)out)[(size_t)row*N + col] = f2bf(g);
        } else {
          ((ushort_t*)out)[(size_t)row*N + col] = f2bf(v);
        }
      }
    }
  }
}

// ---------------- V transpose: qkv v-part -> vt [bh][64][T] ----------------
__global__ __launch_bounds__(256) void vtrans(const ushort_t* __restrict__ qkv,
                                              ushort_t* __restrict__ vt){
  __shared__ __align__(16) ushort_t tile[64*LDSS];
  const int bh = blockIdx.x;
  const int b = bh >> 4, h = bh & 15;
  const int t0 = blockIdx.y*64;
  const int tid = threadIdx.x;
  #pragma unroll
  for (int it = 0; it < 2; ++it){
    int idx = it*256 + tid;                 // 512 chunks of 8
    int i = idx >> 3, c = (idx & 7) << 3;
    uint4 vv = *(const uint4*)(qkv + (size_t)(b*TSEQ + t0 + i)*3072 + 2048 + h*64 + c);
    *(uint4*)(&tile[i*LDSS + c]) = vv;
  }
  __syncthreads();
  #pragma unroll
  for (int it = 0; it < 2; ++it){
    int idx = it*256 + tid;
    int j = idx >> 3, ii = (idx & 7) << 3;
    union { unsigned short us[8]; uint4 u4; } pk;
    #pragma unroll
    for (int e = 0; e < 8; ++e) pk.us[e] = tile[(ii+e)*LDSS + j];
    *(uint4*)(vt + (size_t)(bh*64 + j)*TSEQ + t0 + ii) = pk.u4;
  }
}

// ---------------- flash attention ------------------------------------------
__global__ __launch_bounds__(256) void attn_kernel(const ushort_t* __restrict__ qkv,
                                                   const ushort_t* __restrict__ vt,
                                                   ushort_t* __restrict__ y){
  __shared__ __align__(16) ushort_t Plds[4][16*LDSS];
  const int bh = blockIdx.x;
  const int b = bh >> 4, h = bh & 15;
  const int q0 = blockIdx.y * 64;
  const int wave = threadIdx.x >> 6, lane = threadIdx.x & 63;
  const int quad = lane >> 4, l16 = lane & 15;
  const int qrow0 = q0 + wave*16;

  const ushort_t* qbase = qkv + (size_t)(b*TSEQ)*3072 + h*64;
  const ushort_t* kbase = qbase + 1024;
  const ushort_t* vbase = vt + (size_t)(bh*64)*TSEQ;
  ushort_t* P = Plds[wave];

  bf16x8 qf[2];
  #pragma unroll
  for (int kk = 0; kk < 2; ++kk)
    qf[kk] = *(const bf16x8*)(qbase + (size_t)(qrow0 + l16)*3072 + kk*32 + quad*8);

  float m_i[4], l_i[4];
  f32x4 o[4] = {};
  #pragma unroll
  for (int r = 0; r < 4; ++r){ m_i[r] = -3e38f; l_i[r] = 0.f; }

  const int jend = qrow0 + 15;
  for (int j0 = 0; j0 <= jend; j0 += 64) {
    f32x4 s[4] = {};
    #pragma unroll
    for (int kk = 0; kk < 2; ++kk){
      #pragma unroll
      for (int nj = 0; nj < 4; ++nj){
        bf16x8 kf = *(const bf16x8*)(kbase + (size_t)(j0 + nj*16 + l16)*3072 + kk*32 + quad*8);
        s[nj] = __builtin_amdgcn_mfma_f32_16x16x32_bf16(qf[kk], kf, s[nj], 0,0,0);
      }
    }
    float mt[4] = {-3e38f,-3e38f,-3e38f,-3e38f};
    #pragma unroll
    for (int nj = 0; nj < 4; ++nj){
      #pragma unroll
      for (int r = 0; r < 4; ++r){
        float sv = s[nj][r]*0.125f;                 // 1/sqrt(64)
        int jc = j0 + nj*16 + l16;
        int qr = qrow0 + quad*4 + r;
        sv = (jc > qr) ? -3e38f : sv;               // causal mask
        s[nj][r] = sv;
        mt[r] = fmaxf(mt[r], sv);
      }
    }
    #pragma unroll
    for (int off = 1; off < 16; off <<= 1){
      #pragma unroll
      for (int r = 0; r < 4; ++r) mt[r] = fmaxf(mt[r], __shfl_xor(mt[r], off));
    }
    float alpha[4], rs[4];
    #pragma unroll
    for (int r = 0; r < 4; ++r){
      float mn = fmaxf(m_i[r], mt[r]);
      alpha[r] = __expf(m_i[r] - mn);
      m_i[r] = mn;
      rs[r] = 0.f;
    }
    __threadfence_block();        // prior-iter P reads complete before overwrite
    #pragma unroll
    for (int nj = 0; nj < 4; ++nj){
      #pragma unroll
      for (int r = 0; r < 4; ++r){
        float pv = __expf(s[nj][r] - m_i[r]);
        rs[r] += pv;
        P[(quad*4 + r)*LDSS + nj*16 + l16] = f2bf(pv);   // C-layout -> LDS
      }
    }
    __threadfence_block();        // P writes complete before A-layout reads
    #pragma unroll
    for (int off = 1; off < 16; off <<= 1){
      #pragma unroll
      for (int r = 0; r < 4; ++r) rs[r] += __shfl_xor(rs[r], off);
    }
    #pragma unroll
    for (int r = 0; r < 4; ++r) l_i[r] = l_i[r]*alpha[r] + rs[r];
    #pragma unroll
    for (int dj = 0; dj < 4; ++dj)
      #pragma unroll
      for (int r = 0; r < 4; ++r) o[dj][r] *= alpha[r];
    #pragma unroll
    for (int kk = 0; kk < 2; ++kk){
      bf16x8 pf = *(const bf16x8*)(&P[l16*LDSS + kk*32 + quad*8]);  // A-layout
      #pragma unroll
      for (int dj = 0; dj < 4; ++dj){
        bf16x8 vf = *(const bf16x8*)(vbase + (size_t)(dj*16 + l16)*TSEQ + j0 + kk*32 + quad*8);
        o[dj] = __builtin_amdgcn_mfma_f32_16x16x32_bf16(pf, vf, o[dj], 0,0,0);
      }
    }
  }
  #pragma unroll
  for (int r = 0; r < 4; ++r){
    float inv = 1.0f / l_i[r];
    int t = qrow0 + quad*4 + r;
    ushort_t* yr = y + (size_t)(b*TSEQ + t)*D_MODEL + h*64;
    #pragma unroll
    for (int dj = 0; dj < 4; ++dj)
      yr[dj*16 + l16] = f2bf(o[dj][r] * inv);
  }
}

// ---------------- launcher --------------------------------------------------
extern "C" void kernel_launch(void* const* d_in, const int* in_sizes, int n_in,
                              void* d_out, int out_size, void* d_ws, size_t ws_size,
                              hipStream_t stream)
{
  (void)in_sizes; (void)n_in; (void)out_size; (void)ws_size;
  const float* x      = (const float*)d_in[0];
  const float* ln1_w  = (const float*)d_in[1];
  const float* ln1_b  = (const float*)d_in[2];
  const float* ln2_w  = (const float*)d_in[3];
  const float* ln2_b  = (const float*)d_in[4];
  const float* w_attn = (const float*)d_in[5];
  const float* b_attn = (const float*)d_in[6];
  const float* w_proj = (const float*)d_in[7];
  const float* b_proj = (const float*)d_in[8];
  const float* w_fc   = (const float*)d_in[9];
  const float* b_fc   = (const float*)d_in[10];
  const float* w_fc2  = (const float*)d_in[11];
  const float* b_fc2  = (const float*)d_in[12];
  float* out = (float*)d_out;

  char* p = (char*)d_ws;
  auto alloc = [&](size_t n){ char* r = p; p += (n + 255) & ~(size_t)255; return (void*)r; };
  ushort_t* wAT  = (ushort_t*)alloc((size_t)3072*1024*2);   //  6.3 MB
  ushort_t* wPT  = (ushort_t*)alloc((size_t)1024*1024*2);   //  2.1 MB
  ushort_t* wFT  = (ushort_t*)alloc((size_t)4096*1024*2);   //  8.4 MB
  ushort_t* wF2T = (ushort_t*)alloc((size_t)1024*4096*2);   //  8.4 MB
  ushort_t* hbuf = (ushort_t*)alloc((size_t)NTOK*D_MODEL*2);//  8.4 MB (ln1 out, later ln2 out)
  ushort_t* qkv  = (ushort_t*)alloc((size_t)NTOK*4096*2);   // 33.6 MB (qkv, later fc1 out)
  ushort_t* vt   = (ushort_t*)alloc((size_t)32*64*TSEQ*2);  //  8.4 MB
  ushort_t* ybuf = (ushort_t*)alloc((size_t)NTOK*D_MODEL*2);//  8.4 MB
  float*    x1   = (float*)   alloc((size_t)NTOK*D_MODEL*4);// 16.8 MB
  ushort_t* hh   = qkv;  // fc1 output reuses qkv buffer (free after attention)

  // weights -> bf16 [N][K]
  wtrans<<<dim3(3072/32,1024/32), dim3(32,8), 0, stream>>>(w_attn, wAT, 1024, 3072);
  wtrans<<<dim3(1024/32,1024/32), dim3(32,8), 0, stream>>>(w_proj, wPT, 1024, 1024);
  wtrans<<<dim3(4096/32,1024/32), dim3(32,8), 0, stream>>>(w_fc,  wFT,  1024, 4096);
  wtrans<<<dim3(1024/32,4096/32), dim3(32,8), 0, stream>>>(w_fc2, wF2T, 4096, 1024);

  // LN1
  ln_kernel<<<NTOK, 256, 0, stream>>>(x, ln1_w, ln1_b, hbuf);
  // QKV = h @ w_attn + b_attn           [4096,3072] bf16
  gemm_bt<0><<<dim3(NTOK/128, 3072/128), 256, 0, stream>>>(hbuf, wAT, b_attn, nullptr, qkv, NTOK, 3072, 1024);
  // V^T per head
  vtrans<<<dim3(32, TSEQ/64), 256, 0, stream>>>(qkv, vt);
  // attention -> y [4096,1024] bf16
  attn_kernel<<<dim3(32, TSEQ/64), 256, 0, stream>>>(qkv, vt, ybuf);
  // x1 = x + y @ w_proj + b_proj        fp32
  gemm_bt<1><<<dim3(NTOK/128, 1024/128), 256, 0, stream>>>(ybuf, wPT, b_proj, x, x1, NTOK, 1024, 1024);
  // LN2
  ln_kernel<<<NTOK, 256, 0, stream>>>(x1, ln2_w, ln2_b, hbuf);
  // hh = gelu(h2 @ w_fc + b_fc)         [4096,4096] bf16
  gemm_bt<2><<<dim3(NTOK/128, 4096/128), 256, 0, stream>>>(hbuf, wFT, b_fc, nullptr, hh, NTOK, 4096, 1024);
  // out = x1 + hh @ w_fc2 + b_fc2       fp32
  gemm_bt<1><<<dim3(NTOK/128, 1024/128), 256, 0, stream>>>(hh, wF2T, b_fc2, x1, out, NTOK, 1024, 4096);
}

// Round 2
// 481.596 us; speedup vs baseline: 1.0189x; 1.0189x over previous
//
#include <hip/hip_runtime.h>
#include <cstdint>
#include <cstddef>

// TransformerBlock on MI355X (gfx950). bf16 MFMA everywhere, fp32 spine.
// R2: (1) attention computes S^T (A=K,B=Q) -> per-lane softmax state, 2-step
//     quad reductions, packed b64 P-stores, 64-thr blocks, LPT order.
//     (2) GEMM staging via __builtin_amdgcn_global_load_lds width=16 with
//     XOR-swizzled chunk placement (pad-free LDS, 2-way read conflicts only).

#define D_MODEL 1024
#define TSEQ    2048
#define BATCH   2
#define NHEADS  16
#define NTOK    (BATCH*TSEQ)   // 4096

typedef __attribute__((ext_vector_type(8))) short bf16x8;
typedef __attribute__((ext_vector_type(4))) float f32x4;
typedef unsigned short ushort_t;

#define AS3(p) ((__attribute__((address_space(3))) unsigned int*)(p))
#define AS1(p) ((const __attribute__((address_space(1))) unsigned int*)(p))

__device__ __forceinline__ unsigned short f2bf(float f){
  union { float f; unsigned u; } v; v.f = f;
  unsigned r = v.u + 0x7fffu + ((v.u >> 16) & 1u);
  return (unsigned short)(r >> 16);
}
// pack 2 floats -> 2 bf16 (round-half-up) in one v_perm
__device__ __forceinline__ unsigned pk2bf(float a, float b){
  union { float f; unsigned u; } x, y; x.f = a; y.f = b;
  return __builtin_amdgcn_perm(y.u + 0x8000u, x.u + 0x8000u, 0x07060302u);
}

// ---------------- weight convert + transpose: fp32 [K][N] -> bf16 [N][K] ----
__global__ __launch_bounds__(256) void wtrans(const float* __restrict__ in,
                                              ushort_t* __restrict__ out,
                                              int K, int N){
  __shared__ float tile[32][33];
  int n0 = blockIdx.x*32, k0 = blockIdx.y*32;
  int tx = threadIdx.x, ty = threadIdx.y;   // 32 x 8
  #pragma unroll
  for (int i=0;i<32;i+=8)
    tile[ty+i][tx] = in[(size_t)(k0+ty+i)*N + n0+tx];
  __syncthreads();
  #pragma unroll
  for (int i=0;i<32;i+=8)
    out[(size_t)(n0+ty+i)*K + k0+tx] = f2bf(tile[tx][ty+i]);
}

// ---------------- layernorm: fp32 row[1024] -> bf16 ------------------------
__global__ __launch_bounds__(256) void ln_kernel(const float* __restrict__ x,
                                                 const float* __restrict__ w,
                                                 const float* __restrict__ b,
                                                 ushort_t* __restrict__ out){
  int row = blockIdx.x;
  int tid = threadIdx.x;
  const float* xr = x + (size_t)row*D_MODEL;
  float4 v = ((const float4*)xr)[tid];
  float s  = v.x+v.y+v.z+v.w;
  float s2 = v.x*v.x+v.y*v.y+v.z*v.z+v.w*v.w;
  #pragma unroll
  for (int off=1; off<64; off<<=1){ s += __shfl_xor(s,off); s2 += __shfl_xor(s2,off); }
  __shared__ float ss[4], ss2[4];
  int wave = tid>>6, lane = tid&63;
  if (lane==0){ ss[wave]=s; ss2[wave]=s2; }
  __syncthreads();
  s  = ss[0]+ss[1]+ss[2]+ss[3];
  s2 = ss2[0]+ss2[1]+ss2[2]+ss2[3];
  float mu  = s * (1.0f/D_MODEL);
  float var = s2 * (1.0f/D_MODEL) - mu*mu;
  float rstd = rsqrtf(var + 1e-5f);
  float4 wv = ((const float4*)w)[tid];
  float4 bv = ((const float4*)b)[tid];
  uint2 pk;
  pk.x = pk2bf((v.x-mu)*rstd*wv.x + bv.x, (v.y-mu)*rstd*wv.y + bv.y);
  pk.y = pk2bf((v.z-mu)*rstd*wv.z + bv.z, (v.w-mu)*rstd*wv.w + bv.w);
  *(uint2*)(out + (size_t)row*D_MODEL + tid*4) = pk;
}

// ---------------- GEMM: C[M,N] = A[M,K]bf16 * BT[N,K]bf16^T + epilogue -----
// LDS: pad-free [128 rows][64 cols], 16B chunks XOR-swizzled (pos = c ^ (row&7))
// so global_load_lds (wave-uniform base + lane*16) lands swizzled and the
// ds_read_b128 fragment reads hit 8 distinct bank groups (2-way = free).
// MODE 0: out bf16 = acc + bias
// MODE 1: out f32  = acc + bias + res
// MODE 2: out bf16 = gelu(acc + bias)
template<int MODE>
__global__ __launch_bounds__(256) void gemm_bt(const ushort_t* __restrict__ A,
                                               const ushort_t* __restrict__ BT,
                                               const float* __restrict__ bias,
                                               const float* __restrict__ res,
                                               void* __restrict__ out,
                                               int M, int N, int K){
  __shared__ __align__(16) ushort_t As[128*64];
  __shared__ __align__(16) ushort_t Bs[128*64];
  const int m0 = blockIdx.x*128, n0 = blockIdx.y*128;
  const int tid = threadIdx.x;
  const int wave = tid >> 6, lane = tid & 63;
  const int wm = (wave >> 1)*64, wn = (wave & 1)*64;
  const int quad = lane >> 4, l16 = lane & 15;

  f32x4 acc[4][4] = {};

  for (int k0 = 0; k0 < K; k0 += 64) {
    #pragma unroll
    for (int c = 0; c < 4; ++c) {
      int q   = (c*4 + wave)*64 + lane;       // chunk id 0..1023
      int row = q >> 3;
      int pos = q & 7;
      int lc  = pos ^ (row & 7);              // which global chunk this slot gets
      const ushort_t* ga = A  + (size_t)(m0+row)*K + k0 + lc*8;
      const ushort_t* gb = BT + (size_t)(n0+row)*K + k0 + lc*8;
      __builtin_amdgcn_global_load_lds(AS1(ga), AS3(&As[(c*4+wave)*512]), 16, 0, 0);
      __builtin_amdgcn_global_load_lds(AS1(gb), AS3(&Bs[(c*4+wave)*512]), 16, 0, 0);
    }
    __syncthreads();
    #pragma unroll
    for (int kk = 0; kk < 64; kk += 32) {
      bf16x8 af[4], bfr[4];
      #pragma unroll
      for (int i = 0; i < 4; ++i){
        int row = wm + i*16 + l16;
        int pos = ((kk>>3) + quad) ^ (row & 7);
        af[i] = *(const bf16x8*)(&As[row*64 + pos*8]);
      }
      #pragma unroll
      for (int i = 0; i < 4; ++i){
        int row = wn + i*16 + l16;
        int pos = ((kk>>3) + quad) ^ (row & 7);
        bfr[i] = *(const bf16x8*)(&Bs[row*64 + pos*8]);
      }
      #pragma unroll
      for (int mi = 0; mi < 4; ++mi)
        #pragma unroll
        for (int ni = 0; ni < 4; ++ni)
          acc[mi][ni] = __builtin_amdgcn_mfma_f32_16x16x32_bf16(af[mi], bfr[ni], acc[mi][ni], 0,0,0);
    }
    __syncthreads();
  }

  #pragma unroll
  for (int ni = 0; ni < 4; ++ni){
    int col = n0 + wn + ni*16 + l16;
    float bv = bias[col];
    #pragma unroll
    for (int mi = 0; mi < 4; ++mi){
      #pragma unroll
      for (int r = 0; r < 4; ++r){
        int row = m0 + wm + mi*16 + quad*4 + r;
        float v = acc[mi][ni][r] + bv;
        if constexpr (MODE == 1){
          ((float*)out)[(size_t)row*N + col] = v + res[(size_t)row*N + col];
        } else if constexpr (MODE == 2){
          float g = 0.5f*v*(1.0f + erff(v*0.70710678118654752f));
          ((ushort_t*)out)[(size_t)row*N + col] = f2bf(g);
        } else {
          ((ushort_t*)out)[(size_t)row*N + col] = f2bf(v);
        }
      }
    }
  }
}

// ---------------- V transpose: qkv v-part -> vt [bh][64][T] ----------------
#define LDSS 72
__global__ __launch_bounds__(256) void vtrans(const ushort_t* __restrict__ qkv,
                                              ushort_t* __restrict__ vt){
  __shared__ __align__(16) ushort_t tile[64*LDSS];
  const int bh = blockIdx.x;
  const int b = bh >> 4, h = bh & 15;
  const int t0 = blockIdx.y*64;
  const int tid = threadIdx.x;
  #pragma unroll
  for (int it = 0; it < 2; ++it){
    int idx = it*256 + tid;                 // 512 chunks of 8
    int i = idx >> 3, c = (idx & 7) << 3;
    uint4 vv = *(const uint4*)(qkv + (size_t)(b*TSEQ + t0 + i)*3072 + 2048 + h*64 + c);
    *(uint4*)(&tile[i*LDSS + c]) = vv;
  }
  __syncthreads();
  #pragma unroll
  for (int it = 0; it < 2; ++it){
    int idx = it*256 + tid;
    int j = idx >> 3, ii = (idx & 7) << 3;
    union { unsigned short us[8]; uint4 u4; } pk;
    #pragma unroll
    for (int e = 0; e < 8; ++e) pk.us[e] = tile[(ii+e)*LDSS + j];
    *(uint4*)(vt + (size_t)(bh*64 + j)*TSEQ + t0 + ii) = pk.u4;
  }
}

// ---------------- flash attention (S^T formulation) -------------------------
// One wave per block; wave owns 16 Q rows, lane l16 owns Q row qrow0+l16.
// S^T = K.Q^T (A=K rows j, B=Q rows as cols) -> lane state m,l are scalars.
// O^T = V^T.P^T accumulated in C-layout; P^T packed to LDS [m][j] stride 72.
#define PSTR 72
__global__ __launch_bounds__(64) void attn_kernel(const ushort_t* __restrict__ qkv,
                                                  const ushort_t* __restrict__ vt,
                                                  ushort_t* __restrict__ y){
  __shared__ __align__(16) ushort_t P[16*PSTR];
  const int bh = blockIdx.x;
  const int b = bh >> 4, h = bh & 15;
  const int qtile = 127 - blockIdx.y;            // heavy tiles dispatched first
  const int qrow0 = qtile * 16;
  const int lane = threadIdx.x;
  const int quad = lane >> 4, l16 = lane & 15;

  const ushort_t* qbase = qkv + (size_t)(b*TSEQ)*3072 + h*64;
  const ushort_t* kbase = qbase + 1024;
  const ushort_t* vbase = vt + (size_t)(bh*64)*TSEQ;

  // Q fragment as B-operand: lane = Q row (col of S^T), k = d
  bf16x8 qf[2];
  #pragma unroll
  for (int kk = 0; kk < 2; ++kk)
    qf[kk] = *(const bf16x8*)(qbase + (size_t)(qrow0 + l16)*3072 + kk*32 + quad*8);

  float m_i = -3e38f, l_i = 0.f;
  f32x4 o[4] = {};
  const float c = 0.18033688011112042f;          // (1/sqrt(64)) * log2(e)

  const int nfull = (qrow0 + 1) >> 6;            // tiles fully below diagonal
  int j0 = 0;
  for (int it = 0; it <= nfull; ++it, j0 += 64) {
    // --- S^T tiles: s[nj] holds rows j = j0+nj*16+quad*4+r, col m = l16 ---
    f32x4 s[4] = {};
    #pragma unroll
    for (int kk = 0; kk < 2; ++kk){
      #pragma unroll
      for (int nj = 0; nj < 4; ++nj){
        bf16x8 kf = *(const bf16x8*)(kbase + (size_t)(j0 + nj*16 + l16)*3072 + kk*32 + quad*8);
        s[nj] = __builtin_amdgcn_mfma_f32_16x16x32_bf16(kf, qf[kk], s[nj], 0,0,0);
      }
    }
    if (it == nfull) {                           // only diagonal tile masks
      #pragma unroll
      for (int nj = 0; nj < 4; ++nj)
        #pragma unroll
        for (int r = 0; r < 4; ++r){
          int jc = j0 + nj*16 + quad*4 + r;
          if (jc > qrow0 + l16) s[nj][r] = -3e38f;
        }
    }
    // --- row max: per-lane partial then 2-step quad reduce ---
    float mloc = s[0][0];
    #pragma unroll
    for (int nj = 0; nj < 4; ++nj)
      #pragma unroll
      for (int r = 0; r < 4; ++r) mloc = fmaxf(mloc, s[nj][r]);
    mloc = fmaxf(mloc, __shfl_xor(mloc, 16));
    mloc = fmaxf(mloc, __shfl_xor(mloc, 32));
    float mn = fmaxf(m_i, mloc);
    float alpha = __builtin_amdgcn_exp2f((m_i - mn)*c);
    m_i = mn;
    // --- p = exp2((s-m)*c), pack 4 -> b64 LDS store, accumulate row sum ---
    float rs = 0.f;
    #pragma unroll
    for (int nj = 0; nj < 4; ++nj){
      float p0 = __builtin_amdgcn_exp2f((s[nj][0]-mn)*c);
      float p1 = __builtin_amdgcn_exp2f((s[nj][1]-mn)*c);
      float p2 = __builtin_amdgcn_exp2f((s[nj][2]-mn)*c);
      float p3 = __builtin_amdgcn_exp2f((s[nj][3]-mn)*c);
      rs += (p0+p1)+(p2+p3);
      uint2 pk; pk.x = pk2bf(p0,p1); pk.y = pk2bf(p2,p3);
      *(uint2*)(&P[l16*PSTR + nj*16 + quad*4]) = pk;     // P[m][j], 8B aligned
    }
    rs += __shfl_xor(rs, 16);
    rs += __shfl_xor(rs, 32);
    l_i = l_i*alpha + rs;
    #pragma unroll
    for (int dj = 0; dj < 4; ++dj)
      #pragma unroll
      for (int r = 0; r < 4; ++r) o[dj][r] *= alpha;
    // --- O^T += V^T . P^T ---
    bf16x8 pf[2];
    #pragma unroll
    for (int kk = 0; kk < 2; ++kk)
      pf[kk] = *(const bf16x8*)(&P[l16*PSTR + kk*32 + quad*8]);  // B-operand
    #pragma unroll
    for (int kk = 0; kk < 2; ++kk){
      #pragma unroll
      for (int dj = 0; dj < 4; ++dj){
        bf16x8 vf = *(const bf16x8*)(vbase + (size_t)(dj*16 + l16)*TSEQ + j0 + kk*32 + quad*8);
        o[dj] = __builtin_amdgcn_mfma_f32_16x16x32_bf16(vf, pf[kk], o[dj], 0,0,0);
      }
    }
  }
  // --- epilogue: lane owns Q row t=qrow0+l16; d = dj*16+quad*4+r ---
  float inv = 1.0f / l_i;
  ushort_t* yr = y + (size_t)(b*TSEQ + qrow0 + l16)*D_MODEL + h*64;
  #pragma unroll
  for (int dj = 0; dj < 4; ++dj){
    uint2 pk;
    pk.x = pk2bf(o[dj][0]*inv, o[dj][1]*inv);
    pk.y = pk2bf(o[dj][2]*inv, o[dj][3]*inv);
    *(uint2*)(yr + dj*16 + quad*4) = pk;
  }
}

// ---------------- launcher --------------------------------------------------
extern "C" void kernel_launch(void* const* d_in, const int* in_sizes, int n_in,
                              void* d_out, int out_size, void* d_ws, size_t ws_size,
                              hipStream_t stream)
{
  (void)in_sizes; (void)n_in; (void)out_size; (void)ws_size;
  const float* x      = (const float*)d_in[0];
  const float* ln1_w  = (const float*)d_in[1];
  const float* ln1_b  = (const float*)d_in[2];
  const float* ln2_w  = (const float*)d_in[3];
  const float* ln2_b  = (const float*)d_in[4];
  const float* w_attn = (const float*)d_in[5];
  const float* b_attn = (const float*)d_in[6];
  const float* w_proj = (const float*)d_in[7];
  const float* b_proj = (const float*)d_in[8];
  const float* w_fc   = (const float*)d_in[9];
  const float* b_fc   = (const float*)d_in[10];
  const float* w_fc2  = (const float*)d_in[11];
  const float* b_fc2  = (const float*)d_in[12];
  float* out = (float*)d_out;

  char* p = (char*)d_ws;
  auto alloc = [&](size_t n){ char* r = p; p += (n + 255) & ~(size_t)255; return (void*)r; };
  ushort_t* wAT  = (ushort_t*)alloc((size_t)3072*1024*2);
  ushort_t* wPT  = (ushort_t*)alloc((size_t)1024*1024*2);
  ushort_t* wFT  = (ushort_t*)alloc((size_t)4096*1024*2);
  ushort_t* wF2T = (ushort_t*)alloc((size_t)1024*4096*2);
  ushort_t* hbuf = (ushort_t*)alloc((size_t)NTOK*D_MODEL*2);
  ushort_t* qkv  = (ushort_t*)alloc((size_t)NTOK*4096*2);   // qkv, later fc1 out
  ushort_t* vt   = (ushort_t*)alloc((size_t)32*64*TSEQ*2);
  ushort_t* ybuf = (ushort_t*)alloc((size_t)NTOK*D_MODEL*2);
  float*    x1   = (float*)   alloc((size_t)NTOK*D_MODEL*4);
  ushort_t* hh   = qkv;

  wtrans<<<dim3(3072/32,1024/32), dim3(32,8), 0, stream>>>(w_attn, wAT, 1024, 3072);
  wtrans<<<dim3(1024/32,1024/32), dim3(32,8), 0, stream>>>(w_proj, wPT, 1024, 1024);
  wtrans<<<dim3(4096/32,1024/32), dim3(32,8), 0, stream>>>(w_fc,  wFT,  1024, 4096);
  wtrans<<<dim3(1024/32,4096/32), dim3(32,8), 0, stream>>>(w_fc2, wF2T, 4096, 1024);

  ln_kernel<<<NTOK, 256, 0, stream>>>(x, ln1_w, ln1_b, hbuf);
  gemm_bt<0><<<dim3(NTOK/128, 3072/128), 256, 0, stream>>>(hbuf, wAT, b_attn, nullptr, qkv, NTOK, 3072, 1024);
  vtrans<<<dim3(32, TSEQ/64), 256, 0, stream>>>(qkv, vt);
  attn_kernel<<<dim3(32, TSEQ/16), 64, 0, stream>>>(qkv, vt, ybuf);
  gemm_bt<1><<<dim3(NTOK/128, 1024/128), 256, 0, stream>>>(ybuf, wPT, b_proj, x, x1, NTOK, 1024, 1024);
  ln_kernel<<<NTOK, 256, 0, stream>>>(x1, ln2_w, ln2_b, hbuf);
  gemm_bt<2><<<dim3(NTOK/128, 4096/128), 256, 0, stream>>>(hbuf, wFT, b_fc, nullptr, hh, NTOK, 4096, 1024);
  gemm_bt<1><<<dim3(NTOK/128, 1024/128), 256, 0, stream>>>(hh, wF2T, b_fc2, x1, out, NTOK, 1024, 4096);
}

// Round 4
// 359.648 us; speedup vs baseline: 1.3644x; 1.3391x over previous
//
#include <hip/hip_runtime.h>
#include <cstdint>
#include <cstddef>

// TransformerBlock on MI355X (gfx950). bf16 MFMA everywhere, fp32 spine.
// R4: fix R3's swizzle-index bug in attn LDS reads: fragment k-index kk is
//     {0,1} here (vs element offset {0,32} in gemm), so chunk = kk*4+quad,
//     NOT (kk>>3)+quad. R3 fed K/V d-chunks [0..31] to both k-halves.

#define D_MODEL 1024
#define TSEQ    2048
#define BATCH   2
#define NHEADS  16
#define NTOK    (BATCH*TSEQ)   // 4096

typedef __attribute__((ext_vector_type(8))) short bf16x8;
typedef __attribute__((ext_vector_type(4))) float f32x4;
typedef unsigned short ushort_t;

#define AS3(p) ((__attribute__((address_space(3))) unsigned int*)(p))
#define AS1(p) ((const __attribute__((address_space(1))) unsigned int*)(p))

__device__ __forceinline__ unsigned short f2bf(float f){
  union { float f; unsigned u; } v; v.f = f;
  unsigned r = v.u + 0x7fffu + ((v.u >> 16) & 1u);
  return (unsigned short)(r >> 16);
}
__device__ __forceinline__ unsigned pk2bf(float a, float b){
  union { float f; unsigned u; } x, y; x.f = a; y.f = b;
  return __builtin_amdgcn_perm(y.u + 0x8000u, x.u + 0x8000u, 0x07060302u);
}

// ------------- fused weight convert+transpose: fp32 [K][N] -> bf16 [N][K] ---
__global__ __launch_bounds__(256) void wtrans_all(
    const float* __restrict__ w0, ushort_t* __restrict__ o0,
    const float* __restrict__ w1, ushort_t* __restrict__ o1,
    const float* __restrict__ w2, ushort_t* __restrict__ o2,
    const float* __restrict__ w3, ushort_t* __restrict__ o3){
  __shared__ float tile[32][33];
  int bid = blockIdx.x;
  const float* in; ushort_t* out; int K, N, t;
  if (bid < 3072)      { in=w0; out=o0; K=1024; N=3072; t=bid; }
  else if (bid < 4096) { in=w1; out=o1; K=1024; N=1024; t=bid-3072; }
  else if (bid < 8192) { in=w2; out=o2; K=1024; N=4096; t=bid-4096; }
  else                 { in=w3; out=o3; K=4096; N=1024; t=bid-8192; }
  int tx_n = N >> 5;
  int n0 = (t % tx_n)*32, k0 = (t / tx_n)*32;
  int tx = threadIdx.x & 31, ty = threadIdx.x >> 5;   // 32 x 8
  #pragma unroll
  for (int i=0;i<32;i+=8)
    tile[ty+i][tx] = in[(size_t)(k0+ty+i)*N + n0+tx];
  __syncthreads();
  #pragma unroll
  for (int i=0;i<32;i+=8)
    out[(size_t)(n0+ty+i)*K + k0+tx] = f2bf(tile[tx][ty+i]);
}

// ---------------- layernorm: fp32 row[1024] -> bf16 ------------------------
__global__ __launch_bounds__(256) void ln_kernel(const float* __restrict__ x,
                                                 const float* __restrict__ w,
                                                 const float* __restrict__ b,
                                                 ushort_t* __restrict__ out){
  int row = blockIdx.x;
  int tid = threadIdx.x;
  const float* xr = x + (size_t)row*D_MODEL;
  float4 v = ((const float4*)xr)[tid];
  float s  = v.x+v.y+v.z+v.w;
  float s2 = v.x*v.x+v.y*v.y+v.z*v.z+v.w*v.w;
  #pragma unroll
  for (int off=1; off<64; off<<=1){ s += __shfl_xor(s,off); s2 += __shfl_xor(s2,off); }
  __shared__ float ss[4], ss2[4];
  int wave = tid>>6, lane = tid&63;
  if (lane==0){ ss[wave]=s; ss2[wave]=s2; }
  __syncthreads();
  s  = ss[0]+ss[1]+ss[2]+ss[3];
  s2 = ss2[0]+ss2[1]+ss2[2]+ss2[3];
  float mu  = s * (1.0f/D_MODEL);
  float var = s2 * (1.0f/D_MODEL) - mu*mu;
  float rstd = rsqrtf(var + 1e-5f);
  float4 wv = ((const float4*)w)[tid];
  float4 bv = ((const float4*)b)[tid];
  uint2 pk;
  pk.x = pk2bf((v.x-mu)*rstd*wv.x + bv.x, (v.y-mu)*rstd*wv.y + bv.y);
  pk.y = pk2bf((v.z-mu)*rstd*wv.z + bv.z, (v.w-mu)*rstd*wv.w + bv.w);
  *(uint2*)(out + (size_t)row*D_MODEL + tid*4) = pk;
}

// ---------------- GEMM: C[M,N] = A[M,K]bf16 * BT[N,K]bf16^T + epilogue -----
// 128 x BN tile, 4 waves (2x2). LDS pad-free, 16B chunks XOR-swizzled.
// MODE 0: bf16 = acc+bias | 1: f32 = acc+bias+res | 2: bf16 = gelu(acc+bias)
template<int MODE, int BN>
__global__ __launch_bounds__(256) void gemm_bt(const ushort_t* __restrict__ A,
                                               const ushort_t* __restrict__ BT,
                                               const float* __restrict__ bias,
                                               const float* __restrict__ res,
                                               void* __restrict__ out,
                                               int M, int N, int K){
  constexpr int NI = BN/32;        // acc frags per wave in N
  constexpr int BG = BN/32;        // B staging groups
  __shared__ __align__(16) ushort_t As[128*64];
  __shared__ __align__(16) ushort_t Bs[BN*64];
  const int m0 = blockIdx.x*128, n0 = blockIdx.y*BN;
  const int tid = threadIdx.x;
  const int wave = tid >> 6, lane = tid & 63;
  const int wm = (wave >> 1)*64, wn = (wave & 1)*(BN/2);
  const int quad = lane >> 4, l16 = lane & 15;

  f32x4 acc[4][NI] = {};

  for (int k0 = 0; k0 < K; k0 += 64) {
    #pragma unroll
    for (int c = 0; c < 4; ++c) {
      int q   = (c*4 + wave)*64 + lane;
      int row = q >> 3, pos = q & 7;
      int lc  = pos ^ (row & 7);
      __builtin_amdgcn_global_load_lds(AS1(A + (size_t)(m0+row)*K + k0 + lc*8),
                                       AS3(&As[(c*4+wave)*512]), 16, 0, 0);
    }
    #pragma unroll
    for (int c = 0; c < BG; ++c) {
      int q   = (c*4 + wave)*64 + lane;
      int row = q >> 3, pos = q & 7;
      int lc  = pos ^ (row & 7);
      __builtin_amdgcn_global_load_lds(AS1(BT + (size_t)(n0+row)*K + k0 + lc*8),
                                       AS3(&Bs[(c*4+wave)*512]), 16, 0, 0);
    }
    __syncthreads();
    #pragma unroll
    for (int kk = 0; kk < 64; kk += 32) {
      bf16x8 af[4], bfr[NI];
      #pragma unroll
      for (int i = 0; i < 4; ++i){
        int row = wm + i*16 + l16;
        int pos = ((kk>>3) + quad) ^ (row & 7);     // kk is ELEMENT offset here
        af[i] = *(const bf16x8*)(&As[row*64 + pos*8]);
      }
      #pragma unroll
      for (int i = 0; i < NI; ++i){
        int row = wn + i*16 + l16;
        int pos = ((kk>>3) + quad) ^ (row & 7);
        bfr[i] = *(const bf16x8*)(&Bs[row*64 + pos*8]);
      }
      #pragma unroll
      for (int mi = 0; mi < 4; ++mi)
        #pragma unroll
        for (int ni = 0; ni < NI; ++ni)
          acc[mi][ni] = __builtin_amdgcn_mfma_f32_16x16x32_bf16(af[mi], bfr[ni], acc[mi][ni], 0,0,0);
    }
    __syncthreads();
  }

  #pragma unroll
  for (int ni = 0; ni < NI; ++ni){
    int col = n0 + wn + ni*16 + l16;
    float bv = bias[col];
    #pragma unroll
    for (int mi = 0; mi < 4; ++mi){
      #pragma unroll
      for (int r = 0; r < 4; ++r){
        int row = m0 + wm + mi*16 + quad*4 + r;
        float v = acc[mi][ni][r] + bv;
        if constexpr (MODE == 1){
          ((float*)out)[(size_t)row*N + col] = v + res[(size_t)row*N + col];
        } else if constexpr (MODE == 2){
          float g = 0.5f*v*(1.0f + erff(v*0.70710678118654752f));
          ((ushort_t*)out)[(size_t)row*N + col] = f2bf(g);
        } else {
          ((ushort_t*)out)[(size_t)row*N + col] = f2bf(v);
        }
      }
    }
  }
}

// ---------------- V transpose: qkv v-part -> vt [bh][64][T] ----------------
#define LDSS 72
__global__ __launch_bounds__(256) void vtrans(const ushort_t* __restrict__ qkv,
                                              ushort_t* __restrict__ vt){
  __shared__ __align__(16) ushort_t tile[64*LDSS];
  const int bh = blockIdx.x;
  const int b = bh >> 4, h = bh & 15;
  const int t0 = blockIdx.y*64;
  const int tid = threadIdx.x;
  #pragma unroll
  for (int it = 0; it < 2; ++it){
    int idx = it*256 + tid;
    int i = idx >> 3, c = (idx & 7) << 3;
    uint4 vv = *(const uint4*)(qkv + (size_t)(b*TSEQ + t0 + i)*3072 + 2048 + h*64 + c);
    *(uint4*)(&tile[i*LDSS + c]) = vv;
  }
  __syncthreads();
  #pragma unroll
  for (int it = 0; it < 2; ++it){
    int idx = it*256 + tid;
    int j = idx >> 3, ii = (idx & 7) << 3;
    union { unsigned short us[8]; uint4 u4; } pk;
    #pragma unroll
    for (int e = 0; e < 8; ++e) pk.us[e] = tile[(ii+e)*LDSS + j];
    *(uint4*)(vt + (size_t)(bh*64 + j)*TSEQ + t0 + ii) = pk.u4;
  }
}

// ---------------- flash attention (S^T, 4 waves, LDS K/V dbuf) --------------
#define PSTR 72
__global__ __launch_bounds__(256) void attn_kernel(const ushort_t* __restrict__ qkv,
                                                   const ushort_t* __restrict__ vt,
                                                   ushort_t* __restrict__ y){
  __shared__ __align__(16) ushort_t Ks[2][64*64];
  __shared__ __align__(16) ushort_t Vs[2][64*64];
  __shared__ __align__(16) ushort_t Plds[4][16*PSTR];
  const int bh = blockIdx.x;
  const int b = bh >> 4, h = bh & 15;
  const int qt = (TSEQ/64 - 1) - blockIdx.y;       // heavy tiles first (LPT)
  const int q0 = qt * 64;
  const int wave = threadIdx.x >> 6, lane = threadIdx.x & 63;
  const int quad = lane >> 4, l16 = lane & 15;
  const int qrow = q0 + wave*16 + l16;             // this lane's Q row

  const ushort_t* qbase = qkv + (size_t)(b*TSEQ)*3072 + h*64;
  const ushort_t* kbase = qbase + 1024;
  const ushort_t* vbase = vt + (size_t)(bh*64)*TSEQ;
  ushort_t* P = Plds[wave];

  auto stage = [&](int buf, int j0){
    #pragma unroll
    for (int c = 0; c < 2; ++c){
      int q = (wave*2 + c)*64 + lane;
      int row = q >> 3, pos = q & 7;
      int lc = pos ^ (row & 7);
      __builtin_amdgcn_global_load_lds(AS1(kbase + (size_t)(j0+row)*3072 + lc*8),
                                       AS3(&Ks[buf][(wave*2+c)*512]), 16, 0, 0);
      __builtin_amdgcn_global_load_lds(AS1(vbase + (size_t)row*TSEQ + j0 + lc*8),
                                       AS3(&Vs[buf][(wave*2+c)*512]), 16, 0, 0);
    }
  };

  bf16x8 qf[2];
  #pragma unroll
  for (int kk = 0; kk < 2; ++kk)
    qf[kk] = *(const bf16x8*)(qbase + (size_t)qrow*3072 + kk*32 + quad*8);

  float m_i = -3e38f, l_i = 0.f;
  f32x4 o[4] = {};
  const float cs = 0.18033688011112042f;           // (1/8) * log2(e)

  const int ntiles = qt + 1;
  stage(0, 0);
  for (int it = 0; it < ntiles; ++it) {
    const int cur = it & 1;
    const int j0 = it * 64;
    __syncthreads();                               // staged buf `cur` ready
    if (it + 1 < ntiles) stage(cur ^ 1, j0 + 64);
    // --- S^T = K . Q^T : rows j, col m=l16 ---
    f32x4 s[4] = {};
    #pragma unroll
    for (int kk = 0; kk < 2; ++kk){                // kk is FRAGMENT index {0,1}
      #pragma unroll
      for (int nj = 0; nj < 4; ++nj){
        int row = nj*16 + l16;
        int pos = (kk*4 + quad) ^ (row & 7);       // chunk = kk*4+quad (FIX)
        bf16x8 kf = *(const bf16x8*)(&Ks[cur][row*64 + pos*8]);
        s[nj] = __builtin_amdgcn_mfma_f32_16x16x32_bf16(kf, qf[kk], s[nj], 0,0,0);
      }
    }
    if (it == ntiles-1) {                          // diagonal tile: mask
      #pragma unroll
      for (int nj = 0; nj < 4; ++nj)
        #pragma unroll
        for (int r = 0; r < 4; ++r){
          int jc = j0 + nj*16 + quad*4 + r;
          if (jc > qrow) s[nj][r] = -3e38f;
        }
    }
    float mloc = s[0][0];
    #pragma unroll
    for (int nj = 0; nj < 4; ++nj)
      #pragma unroll
      for (int r = 0; r < 4; ++r) mloc = fmaxf(mloc, s[nj][r]);
    mloc = fmaxf(mloc, __shfl_xor(mloc, 16));
    mloc = fmaxf(mloc, __shfl_xor(mloc, 32));
    float mn = fmaxf(m_i, mloc);
    float alpha = __builtin_amdgcn_exp2f((m_i - mn)*cs);
    m_i = mn;
    float rs = 0.f;
    #pragma unroll
    for (int nj = 0; nj < 4; ++nj){
      float p0 = __builtin_amdgcn_exp2f((s[nj][0]-mn)*cs);
      float p1 = __builtin_amdgcn_exp2f((s[nj][1]-mn)*cs);
      float p2 = __builtin_amdgcn_exp2f((s[nj][2]-mn)*cs);
      float p3 = __builtin_amdgcn_exp2f((s[nj][3]-mn)*cs);
      rs += (p0+p1)+(p2+p3);
      uint2 pk; pk.x = pk2bf(p0,p1); pk.y = pk2bf(p2,p3);
      *(uint2*)(&P[l16*PSTR + nj*16 + quad*4]) = pk;   // P^T[m][j]
    }
    rs += __shfl_xor(rs, 16);
    rs += __shfl_xor(rs, 32);
    l_i = l_i*alpha + rs;
    #pragma unroll
    for (int dj = 0; dj < 4; ++dj)
      #pragma unroll
      for (int r = 0; r < 4; ++r) o[dj][r] *= alpha;
    // --- O^T += V^T . P^T ---
    bf16x8 pf[2];
    #pragma unroll
    for (int kk = 0; kk < 2; ++kk)
      pf[kk] = *(const bf16x8*)(&P[l16*PSTR + kk*32 + quad*8]);
    #pragma unroll
    for (int kk = 0; kk < 2; ++kk){
      #pragma unroll
      for (int dj = 0; dj < 4; ++dj){
        int row = dj*16 + l16;
        int pos = (kk*4 + quad) ^ (row & 7);       // chunk = kk*4+quad (FIX)
        bf16x8 vf = *(const bf16x8*)(&Vs[cur][row*64 + pos*8]);
        o[dj] = __builtin_amdgcn_mfma_f32_16x16x32_bf16(vf, pf[kk], o[dj], 0,0,0);
      }
    }
  }
  float inv = 1.0f / l_i;
  ushort_t* yr = y + (size_t)(b*TSEQ + qrow)*D_MODEL + h*64;
  #pragma unroll
  for (int dj = 0; dj < 4; ++dj){
    uint2 pk;
    pk.x = pk2bf(o[dj][0]*inv, o[dj][1]*inv);
    pk.y = pk2bf(o[dj][2]*inv, o[dj][3]*inv);
    *(uint2*)(yr + dj*16 + quad*4) = pk;
  }
}

// ---------------- launcher --------------------------------------------------
extern "C" void kernel_launch(void* const* d_in, const int* in_sizes, int n_in,
                              void* d_out, int out_size, void* d_ws, size_t ws_size,
                              hipStream_t stream)
{
  (void)in_sizes; (void)n_in; (void)out_size; (void)ws_size;
  const float* x      = (const float*)d_in[0];
  const float* ln1_w  = (const float*)d_in[1];
  const float* ln1_b  = (const float*)d_in[2];
  const float* ln2_w  = (const float*)d_in[3];
  const float* ln2_b  = (const float*)d_in[4];
  const float* w_attn = (const float*)d_in[5];
  const float* b_attn = (const float*)d_in[6];
  const float* w_proj = (const float*)d_in[7];
  const float* b_proj = (const float*)d_in[8];
  const float* w_fc   = (const float*)d_in[9];
  const float* b_fc   = (const float*)d_in[10];
  const float* w_fc2  = (const float*)d_in[11];
  const float* b_fc2  = (const float*)d_in[12];
  float* out = (float*)d_out;

  char* p = (char*)d_ws;
  auto alloc = [&](size_t n){ char* r = p; p += (n + 255) & ~(size_t)255; return (void*)r; };
  ushort_t* wAT  = (ushort_t*)alloc((size_t)3072*1024*2);
  ushort_t* wPT  = (ushort_t*)alloc((size_t)1024*1024*2);
  ushort_t* wFT  = (ushort_t*)alloc((size_t)4096*1024*2);
  ushort_t* wF2T = (ushort_t*)alloc((size_t)1024*4096*2);
  ushort_t* hbuf = (ushort_t*)alloc((size_t)NTOK*D_MODEL*2);
  ushort_t* qkv  = (ushort_t*)alloc((size_t)NTOK*4096*2);   // qkv, later fc1 out
  ushort_t* vt   = (ushort_t*)alloc((size_t)32*64*TSEQ*2);
  ushort_t* ybuf = (ushort_t*)alloc((size_t)NTOK*D_MODEL*2);
  float*    x1   = (float*)   alloc((size_t)NTOK*D_MODEL*4);
  ushort_t* hh   = qkv;

  wtrans_all<<<12288, 256, 0, stream>>>(w_attn, wAT, w_proj, wPT, w_fc, wFT, w_fc2, wF2T);

  ln_kernel<<<NTOK, 256, 0, stream>>>(x, ln1_w, ln1_b, hbuf);
  gemm_bt<0,128><<<dim3(NTOK/128, 3072/128), 256, 0, stream>>>(hbuf, wAT, b_attn, nullptr, qkv, NTOK, 3072, 1024);
  vtrans<<<dim3(32, TSEQ/64), 256, 0, stream>>>(qkv, vt);
  attn_kernel<<<dim3(32, TSEQ/64), 256, 0, stream>>>(qkv, vt, ybuf);
  gemm_bt<1,64><<<dim3(NTOK/128, 1024/64), 256, 0, stream>>>(ybuf, wPT, b_proj, x, x1, NTOK, 1024, 1024);
  ln_kernel<<<NTOK, 256, 0, stream>>>(x1, ln2_w, ln2_b, hbuf);
  gemm_bt<2,128><<<dim3(NTOK/128, 4096/128), 256, 0, stream>>>(hbuf, wFT, b_fc, nullptr, hh, NTOK, 4096, 1024);
  gemm_bt<1,64><<<dim3(NTOK/128, 1024/64), 256, 0, stream>>>(hh, wF2T, b_fc2, x1, out, NTOK, 1024, 4096);
}

// Round 5
// 347.198 us; speedup vs baseline: 1.4133x; 1.0359x over previous
//
#include <hip/hip_runtime.h>
#include <cstdint>
#include <cstddef>

// TransformerBlock on MI355X (gfx950). bf16 MFMA everywhere, fp32 spine.
// R5: gemm_bt computes C^T in-register (mfma operand swap; first operand's
//     l16-row -> output quad*4+r dim, m89/m74-verified) so each lane owns 4
//     consecutive N columns -> vectorized epilogue (uint2/float4 stores,
//     float4 bias), and __launch_bounds__(256,4) to cap at 64+64 regs for
//     16 waves/CU. Attention/LN/vtrans/wtrans unchanged from R4.

#define D_MODEL 1024
#define TSEQ    2048
#define BATCH   2
#define NHEADS  16
#define NTOK    (BATCH*TSEQ)   // 4096

typedef __attribute__((ext_vector_type(8))) short bf16x8;
typedef __attribute__((ext_vector_type(4))) float f32x4;
typedef unsigned short ushort_t;

#define AS3(p) ((__attribute__((address_space(3))) unsigned int*)(p))
#define AS1(p) ((const __attribute__((address_space(1))) unsigned int*)(p))

__device__ __forceinline__ unsigned short f2bf(float f){
  union { float f; unsigned u; } v; v.f = f;
  unsigned r = v.u + 0x7fffu + ((v.u >> 16) & 1u);
  return (unsigned short)(r >> 16);
}
__device__ __forceinline__ unsigned pk2bf(float a, float b){
  union { float f; unsigned u; } x, y; x.f = a; y.f = b;
  return __builtin_amdgcn_perm(y.u + 0x8000u, x.u + 0x8000u, 0x07060302u);
}

// ------------- fused weight convert+transpose: fp32 [K][N] -> bf16 [N][K] ---
__global__ __launch_bounds__(256) void wtrans_all(
    const float* __restrict__ w0, ushort_t* __restrict__ o0,
    const float* __restrict__ w1, ushort_t* __restrict__ o1,
    const float* __restrict__ w2, ushort_t* __restrict__ o2,
    const float* __restrict__ w3, ushort_t* __restrict__ o3){
  __shared__ float tile[32][33];
  int bid = blockIdx.x;
  const float* in; ushort_t* out; int K, N, t;
  if (bid < 3072)      { in=w0; out=o0; K=1024; N=3072; t=bid; }
  else if (bid < 4096) { in=w1; out=o1; K=1024; N=1024; t=bid-3072; }
  else if (bid < 8192) { in=w2; out=o2; K=1024; N=4096; t=bid-4096; }
  else                 { in=w3; out=o3; K=4096; N=1024; t=bid-8192; }
  int tx_n = N >> 5;
  int n0 = (t % tx_n)*32, k0 = (t / tx_n)*32;
  int tx = threadIdx.x & 31, ty = threadIdx.x >> 5;   // 32 x 8
  #pragma unroll
  for (int i=0;i<32;i+=8)
    tile[ty+i][tx] = in[(size_t)(k0+ty+i)*N + n0+tx];
  __syncthreads();
  #pragma unroll
  for (int i=0;i<32;i+=8)
    out[(size_t)(n0+ty+i)*K + k0+tx] = f2bf(tile[tx][ty+i]);
}

// ---------------- layernorm: fp32 row[1024] -> bf16 ------------------------
__global__ __launch_bounds__(256) void ln_kernel(const float* __restrict__ x,
                                                 const float* __restrict__ w,
                                                 const float* __restrict__ b,
                                                 ushort_t* __restrict__ out){
  int row = blockIdx.x;
  int tid = threadIdx.x;
  const float* xr = x + (size_t)row*D_MODEL;
  float4 v = ((const float4*)xr)[tid];
  float s  = v.x+v.y+v.z+v.w;
  float s2 = v.x*v.x+v.y*v.y+v.z*v.z+v.w*v.w;
  #pragma unroll
  for (int off=1; off<64; off<<=1){ s += __shfl_xor(s,off); s2 += __shfl_xor(s2,off); }
  __shared__ float ss[4], ss2[4];
  int wave = tid>>6, lane = tid&63;
  if (lane==0){ ss[wave]=s; ss2[wave]=s2; }
  __syncthreads();
  s  = ss[0]+ss[1]+ss[2]+ss[3];
  s2 = ss2[0]+ss2[1]+ss2[2]+ss2[3];
  float mu  = s * (1.0f/D_MODEL);
  float var = s2 * (1.0f/D_MODEL) - mu*mu;
  float rstd = rsqrtf(var + 1e-5f);
  float4 wv = ((const float4*)w)[tid];
  float4 bv = ((const float4*)b)[tid];
  uint2 pk;
  pk.x = pk2bf((v.x-mu)*rstd*wv.x + bv.x, (v.y-mu)*rstd*wv.y + bv.y);
  pk.y = pk2bf((v.z-mu)*rstd*wv.z + bv.z, (v.w-mu)*rstd*wv.w + bv.w);
  *(uint2*)(out + (size_t)row*D_MODEL + tid*4) = pk;
}

// ---------------- GEMM: C[M,N] = A[M,K]bf16 * BT[N,K]bf16^T + epilogue -----
// 128 x BN tile, 4 waves (2x2). LDS pad-free, 16B chunks XOR-swizzled.
// Accumulates C^T: acc[mi][ni] row-dim = N (quad*4+r), col-dim = M (l16).
// MODE 0: bf16 = acc+bias | 1: f32 = acc+bias+res | 2: bf16 = gelu(acc+bias)
template<int MODE, int BN>
__global__ __launch_bounds__(256, 4) void gemm_bt(const ushort_t* __restrict__ A,
                                                  const ushort_t* __restrict__ BT,
                                                  const float* __restrict__ bias,
                                                  const float* __restrict__ res,
                                                  void* __restrict__ out,
                                                  int M, int N, int K){
  constexpr int NI = BN/32;        // acc frags per wave in N
  constexpr int BG = BN/32;        // B staging groups
  __shared__ __align__(16) ushort_t As[128*64];
  __shared__ __align__(16) ushort_t Bs[BN*64];
  const int m0 = blockIdx.x*128, n0 = blockIdx.y*BN;
  const int tid = threadIdx.x;
  const int wave = tid >> 6, lane = tid & 63;
  const int wm = (wave >> 1)*64, wn = (wave & 1)*(BN/2);
  const int quad = lane >> 4, l16 = lane & 15;

  f32x4 acc[4][NI] = {};

  for (int k0 = 0; k0 < K; k0 += 64) {
    #pragma unroll
    for (int c = 0; c < 4; ++c) {
      int q   = (c*4 + wave)*64 + lane;
      int row = q >> 3, pos = q & 7;
      int lc  = pos ^ (row & 7);
      __builtin_amdgcn_global_load_lds(AS1(A + (size_t)(m0+row)*K + k0 + lc*8),
                                       AS3(&As[(c*4+wave)*512]), 16, 0, 0);
    }
    #pragma unroll
    for (int c = 0; c < BG; ++c) {
      int q   = (c*4 + wave)*64 + lane;
      int row = q >> 3, pos = q & 7;
      int lc  = pos ^ (row & 7);
      __builtin_amdgcn_global_load_lds(AS1(BT + (size_t)(n0+row)*K + k0 + lc*8),
                                       AS3(&Bs[(c*4+wave)*512]), 16, 0, 0);
    }
    __syncthreads();
    #pragma unroll
    for (int kk = 0; kk < 64; kk += 32) {
      bf16x8 af[4], bfr[NI];
      #pragma unroll
      for (int i = 0; i < 4; ++i){
        int row = wm + i*16 + l16;
        int pos = ((kk>>3) + quad) ^ (row & 7);     // kk is ELEMENT offset here
        af[i] = *(const bf16x8*)(&As[row*64 + pos*8]);
      }
      #pragma unroll
      for (int i = 0; i < NI; ++i){
        int row = wn + i*16 + l16;
        int pos = ((kk>>3) + quad) ^ (row & 7);
        bfr[i] = *(const bf16x8*)(&Bs[row*64 + pos*8]);
      }
      #pragma unroll
      for (int mi = 0; mi < 4; ++mi)
        #pragma unroll
        for (int ni = 0; ni < NI; ++ni)
          acc[mi][ni] = __builtin_amdgcn_mfma_f32_16x16x32_bf16(bfr[ni], af[mi], acc[mi][ni], 0,0,0);
    }
    __syncthreads();
  }

  // epilogue: lane owns rows m (l16) x 4 consecutive cols n (quad*4+r)
  #pragma unroll
  for (int ni = 0; ni < NI; ++ni){
    int nb = n0 + wn + ni*16 + quad*4;
    float4 b4 = *(const float4*)(bias + nb);
    #pragma unroll
    for (int mi = 0; mi < 4; ++mi){
      int row = m0 + wm + mi*16 + l16;
      float v0 = acc[mi][ni][0] + b4.x;
      float v1 = acc[mi][ni][1] + b4.y;
      float v2 = acc[mi][ni][2] + b4.z;
      float v3 = acc[mi][ni][3] + b4.w;
      if constexpr (MODE == 1){
        const float4 r4 = *(const float4*)(res + (size_t)row*N + nb);
        float4 o4 = make_float4(v0+r4.x, v1+r4.y, v2+r4.z, v3+r4.w);
        *(float4*)((float*)out + (size_t)row*N + nb) = o4;
      } else if constexpr (MODE == 2){
        float g0 = 0.5f*v0*(1.0f + erff(v0*0.70710678118654752f));
        float g1 = 0.5f*v1*(1.0f + erff(v1*0.70710678118654752f));
        float g2 = 0.5f*v2*(1.0f + erff(v2*0.70710678118654752f));
        float g3 = 0.5f*v3*(1.0f + erff(v3*0.70710678118654752f));
        uint2 pk; pk.x = pk2bf(g0,g1); pk.y = pk2bf(g2,g3);
        *(uint2*)((ushort_t*)out + (size_t)row*N + nb) = pk;
      } else {
        uint2 pk; pk.x = pk2bf(v0,v1); pk.y = pk2bf(v2,v3);
        *(uint2*)((ushort_t*)out + (size_t)row*N + nb) = pk;
      }
    }
  }
}

// ---------------- V transpose: qkv v-part -> vt [bh][64][T] ----------------
#define LDSS 72
__global__ __launch_bounds__(256) void vtrans(const ushort_t* __restrict__ qkv,
                                              ushort_t* __restrict__ vt){
  __shared__ __align__(16) ushort_t tile[64*LDSS];
  const int bh = blockIdx.x;
  const int b = bh >> 4, h = bh & 15;
  const int t0 = blockIdx.y*64;
  const int tid = threadIdx.x;
  #pragma unroll
  for (int it = 0; it < 2; ++it){
    int idx = it*256 + tid;
    int i = idx >> 3, c = (idx & 7) << 3;
    uint4 vv = *(const uint4*)(qkv + (size_t)(b*TSEQ + t0 + i)*3072 + 2048 + h*64 + c);
    *(uint4*)(&tile[i*LDSS + c]) = vv;
  }
  __syncthreads();
  #pragma unroll
  for (int it = 0; it < 2; ++it){
    int idx = it*256 + tid;
    int j = idx >> 3, ii = (idx & 7) << 3;
    union { unsigned short us[8]; uint4 u4; } pk;
    #pragma unroll
    for (int e = 0; e < 8; ++e) pk.us[e] = tile[(ii+e)*LDSS + j];
    *(uint4*)(vt + (size_t)(bh*64 + j)*TSEQ + t0 + ii) = pk.u4;
  }
}

// ---------------- flash attention (S^T, 4 waves, LDS K/V dbuf) --------------
#define PSTR 72
__global__ __launch_bounds__(256) void attn_kernel(const ushort_t* __restrict__ qkv,
                                                   const ushort_t* __restrict__ vt,
                                                   ushort_t* __restrict__ y){
  __shared__ __align__(16) ushort_t Ks[2][64*64];
  __shared__ __align__(16) ushort_t Vs[2][64*64];
  __shared__ __align__(16) ushort_t Plds[4][16*PSTR];
  const int bh = blockIdx.x;
  const int b = bh >> 4, h = bh & 15;
  const int qt = (TSEQ/64 - 1) - blockIdx.y;       // heavy tiles first (LPT)
  const int q0 = qt * 64;
  const int wave = threadIdx.x >> 6, lane = threadIdx.x & 63;
  const int quad = lane >> 4, l16 = lane & 15;
  const int qrow = q0 + wave*16 + l16;             // this lane's Q row

  const ushort_t* qbase = qkv + (size_t)(b*TSEQ)*3072 + h*64;
  const ushort_t* kbase = qbase + 1024;
  const ushort_t* vbase = vt + (size_t)(bh*64)*TSEQ;
  ushort_t* P = Plds[wave];

  auto stage = [&](int buf, int j0){
    #pragma unroll
    for (int c = 0; c < 2; ++c){
      int q = (wave*2 + c)*64 + lane;
      int row = q >> 3, pos = q & 7;
      int lc = pos ^ (row & 7);
      __builtin_amdgcn_global_load_lds(AS1(kbase + (size_t)(j0+row)*3072 + lc*8),
                                       AS3(&Ks[buf][(wave*2+c)*512]), 16, 0, 0);
      __builtin_amdgcn_global_load_lds(AS1(vbase + (size_t)row*TSEQ + j0 + lc*8),
                                       AS3(&Vs[buf][(wave*2+c)*512]), 16, 0, 0);
    }
  };

  bf16x8 qf[2];
  #pragma unroll
  for (int kk = 0; kk < 2; ++kk)
    qf[kk] = *(const bf16x8*)(qbase + (size_t)qrow*3072 + kk*32 + quad*8);

  float m_i = -3e38f, l_i = 0.f;
  f32x4 o[4] = {};
  const float cs = 0.18033688011112042f;           // (1/8) * log2(e)

  const int ntiles = qt + 1;
  stage(0, 0);
  for (int it = 0; it < ntiles; ++it) {
    const int cur = it & 1;
    const int j0 = it * 64;
    __syncthreads();                               // staged buf `cur` ready
    if (it + 1 < ntiles) stage(cur ^ 1, j0 + 64);
    // --- S^T = K . Q^T : rows j, col m=l16 ---
    f32x4 s[4] = {};
    #pragma unroll
    for (int kk = 0; kk < 2; ++kk){                // kk is FRAGMENT index {0,1}
      #pragma unroll
      for (int nj = 0; nj < 4; ++nj){
        int row = nj*16 + l16;
        int pos = (kk*4 + quad) ^ (row & 7);
        bf16x8 kf = *(const bf16x8*)(&Ks[cur][row*64 + pos*8]);
        s[nj] = __builtin_amdgcn_mfma_f32_16x16x32_bf16(kf, qf[kk], s[nj], 0,0,0);
      }
    }
    if (it == ntiles-1) {                          // diagonal tile: mask
      #pragma unroll
      for (int nj = 0; nj < 4; ++nj)
        #pragma unroll
        for (int r = 0; r < 4; ++r){
          int jc = j0 + nj*16 + quad*4 + r;
          if (jc > qrow) s[nj][r] = -3e38f;
        }
    }
    float mloc = s[0][0];
    #pragma unroll
    for (int nj = 0; nj < 4; ++nj)
      #pragma unroll
      for (int r = 0; r < 4; ++r) mloc = fmaxf(mloc, s[nj][r]);
    mloc = fmaxf(mloc, __shfl_xor(mloc, 16));
    mloc = fmaxf(mloc, __shfl_xor(mloc, 32));
    float mn = fmaxf(m_i, mloc);
    float alpha = __builtin_amdgcn_exp2f((m_i - mn)*cs);
    m_i = mn;
    float rs = 0.f;
    #pragma unroll
    for (int nj = 0; nj < 4; ++nj){
      float p0 = __builtin_amdgcn_exp2f((s[nj][0]-mn)*cs);
      float p1 = __builtin_amdgcn_exp2f((s[nj][1]-mn)*cs);
      float p2 = __builtin_amdgcn_exp2f((s[nj][2]-mn)*cs);
      float p3 = __builtin_amdgcn_exp2f((s[nj][3]-mn)*cs);
      rs += (p0+p1)+(p2+p3);
      uint2 pk; pk.x = pk2bf(p0,p1); pk.y = pk2bf(p2,p3);
      *(uint2*)(&P[l16*PSTR + nj*16 + quad*4]) = pk;   // P^T[m][j]
    }
    rs += __shfl_xor(rs, 16);
    rs += __shfl_xor(rs, 32);
    l_i = l_i*alpha + rs;
    #pragma unroll
    for (int dj = 0; dj < 4; ++dj)
      #pragma unroll
      for (int r = 0; r < 4; ++r) o[dj][r] *= alpha;
    // --- O^T += V^T . P^T ---
    bf16x8 pf[2];
    #pragma unroll
    for (int kk = 0; kk < 2; ++kk)
      pf[kk] = *(const bf16x8*)(&P[l16*PSTR + kk*32 + quad*8]);
    #pragma unroll
    for (int kk = 0; kk < 2; ++kk){
      #pragma unroll
      for (int dj = 0; dj < 4; ++dj){
        int row = dj*16 + l16;
        int pos = (kk*4 + quad) ^ (row & 7);
        bf16x8 vf = *(const bf16x8*)(&Vs[cur][row*64 + pos*8]);
        o[dj] = __builtin_amdgcn_mfma_f32_16x16x32_bf16(vf, pf[kk], o[dj], 0,0,0);
      }
    }
  }
  float inv = 1.0f / l_i;
  ushort_t* yr = y + (size_t)(b*TSEQ + qrow)*D_MODEL + h*64;
  #pragma unroll
  for (int dj = 0; dj < 4; ++dj){
    uint2 pk;
    pk.x = pk2bf(o[dj][0]*inv, o[dj][1]*inv);
    pk.y = pk2bf(o[dj][2]*inv, o[dj][3]*inv);
    *(uint2*)(yr + dj*16 + quad*4) = pk;
  }
}

// ---------------- launcher --------------------------------------------------
extern "C" void kernel_launch(void* const* d_in, const int* in_sizes, int n_in,
                              void* d_out, int out_size, void* d_ws, size_t ws_size,
                              hipStream_t stream)
{
  (void)in_sizes; (void)n_in; (void)out_size; (void)ws_size;
  const float* x      = (const float*)d_in[0];
  const float* ln1_w  = (const float*)d_in[1];
  const float* ln1_b  = (const float*)d_in[2];
  const float* ln2_w  = (const float*)d_in[3];
  const float* ln2_b  = (const float*)d_in[4];
  const float* w_attn = (const float*)d_in[5];
  const float* b_attn = (const float*)d_in[6];
  const float* w_proj = (const float*)d_in[7];
  const float* b_proj = (const float*)d_in[8];
  const float* w_fc   = (const float*)d_in[9];
  const float* b_fc   = (const float*)d_in[10];
  const float* w_fc2  = (const float*)d_in[11];
  const float* b_fc2  = (const float*)d_in[12];
  float* out = (float*)d_out;

  char* p = (char*)d_ws;
  auto alloc = [&](size_t n){ char* r = p; p += (n + 255) & ~(size_t)255; return (void*)r; };
  ushort_t* wAT  = (ushort_t*)alloc((size_t)3072*1024*2);
  ushort_t* wPT  = (ushort_t*)alloc((size_t)1024*1024*2);
  ushort_t* wFT  = (ushort_t*)alloc((size_t)4096*1024*2);
  ushort_t* wF2T = (ushort_t*)alloc((size_t)1024*4096*2);
  ushort_t* hbuf = (ushort_t*)alloc((size_t)NTOK*D_MODEL*2);
  ushort_t* qkv  = (ushort_t*)alloc((size_t)NTOK*4096*2);   // qkv, later fc1 out
  ushort_t* vt   = (ushort_t*)alloc((size_t)32*64*TSEQ*2);
  ushort_t* ybuf = (ushort_t*)alloc((size_t)NTOK*D_MODEL*2);
  float*    x1   = (float*)   alloc((size_t)NTOK*D_MODEL*4);
  ushort_t* hh   = qkv;

  wtrans_all<<<12288, 256, 0, stream>>>(w_attn, wAT, w_proj, wPT, w_fc, wFT, w_fc2, wF2T);

  ln_kernel<<<NTOK, 256, 0, stream>>>(x, ln1_w, ln1_b, hbuf);
  gemm_bt<0,128><<<dim3(NTOK/128, 3072/128), 256, 0, stream>>>(hbuf, wAT, b_attn, nullptr, qkv, NTOK, 3072, 1024);
  vtrans<<<dim3(32, TSEQ/64), 256, 0, stream>>>(qkv, vt);
  attn_kernel<<<dim3(32, TSEQ/64), 256, 0, stream>>>(qkv, vt, ybuf);
  gemm_bt<1,64><<<dim3(NTOK/128, 1024/64), 256, 0, stream>>>(ybuf, wPT, b_proj, x, x1, NTOK, 1024, 1024);
  ln_kernel<<<NTOK, 256, 0, stream>>>(x1, ln2_w, ln2_b, hbuf);
  gemm_bt<2,128><<<dim3(NTOK/128, 4096/128), 256, 0, stream>>>(hbuf, wFT, b_fc, nullptr, hh, NTOK, 4096, 1024);
  gemm_bt<1,64><<<dim3(NTOK/128, 1024/64), 256, 0, stream>>>(hh, wF2T, b_fc2, x1, out, NTOK, 1024, 4096);
}